// Round 11
// baseline (557.112 us; speedup 1.0000x reference)
//
#include <hip/hip_runtime.h>

// Collapsed problem (channel-sum commutes with the linear conv):
//   out[n,d,h,w] = sum_{i,kd,kh,kw} x[n,i,d+kd,h+kh,w+kw] * Wsum[i,kd,kh,kw] + C
//   Wsum = 0.5 * sum_o conv_weight[o,...]; C = sum_o (0.5*cb[o] + pb[o])
// x: (8,32,32,64,64) fp32; out: (8,30,62,62) fp32.
//
// R11: register-direct + 1-channel-ahead pipeline, FULLY SCALARIZED.
// R10's WRITE_SIZE=705MB / VGPR=64 proved the float4[9] arrays went to
// scratch (SROA failure -> spill pump). Here: 18 named float4s, 9 named
// offsets, macro-expanded loads/FMAs, named acc0..3 -> nothing indexable,
// nothing spillable. Schedule: LOAD B(ch+1); COMPUTE A(ch); LOAD A(ch+2);
// COMPUTE B(ch+1) -- first use of a set waits vmcnt(9), other set in flight.

#define XD 32
#define XH 64
#define XW 64
#define DOUT 30
#define HOUT 62
#define WOUT 62
#define CH_STRIDE (XD * XH * XW)

__device__ __forceinline__ float nextlane(float v) {
  // row_shl:1 -> lane i gets lane i+1 (16-lane row); bound_ctrl=true: lanes
  // 15/31/47/63 read 0 -> feeds only epilogue-masked outputs (s=15).
  return __int_as_float(
      __builtin_amdgcn_mov_dpp(__float_as_int(v), 0x101, 0xF, 0xF, true));
}

// acc update for one input row av with taps (t0,t1,t2):
//   acc[j] += xv[j]*t0 + xv[j+1]*t1 + xv[j+2]*t2, xv = {av.xyzw, lane+1's x,y}
#define ROWFMA(av, t0, t1, t2)                                        \
  do {                                                                \
    const float4 _av = (av);                                          \
    const float _x4 = nextlane(_av.x);                                \
    const float _x5 = nextlane(_av.y);                                \
    acc0 = fmaf(_av.x, (t0), fmaf(_av.y, (t1), fmaf(_av.z, (t2), acc0))); \
    acc1 = fmaf(_av.y, (t0), fmaf(_av.z, (t1), fmaf(_av.w, (t2), acc1))); \
    acc2 = fmaf(_av.z, (t0), fmaf(_av.w, (t1), fmaf(_x4,  (t2), acc2))); \
    acc3 = fmaf(_av.w, (t0), fmaf(_x4,  (t1), fmaf(_x5,  (t2), acc3))); \
  } while (0)

#define LOAD_SET(p, v0, v1, v2, v3, v4, v5, v6, v7, v8)  \
  do {                                                   \
    v0 = *(const float4*)((p) + o0);                     \
    v1 = *(const float4*)((p) + o1);                     \
    v2 = *(const float4*)((p) + o2);                     \
    v3 = *(const float4*)((p) + o3);                     \
    v4 = *(const float4*)((p) + o4);                     \
    v5 = *(const float4*)((p) + o5);                     \
    v6 = *(const float4*)((p) + o6);                     \
    v7 = *(const float4*)((p) + o7);                     \
    v8 = *(const float4*)((p) + o8);                     \
  } while (0)

// one kd-block (9 taps at wrow + kd*16) applied to rows v0,v1,v2
#define KD_BLOCK(wrow, kdoff, v0, v1, v2)                 \
  do {                                                    \
    const float4 _wA = *(const float4*)((wrow) + (kdoff));     \
    const float4 _wB = *(const float4*)((wrow) + (kdoff) + 4); \
    const float  _w8 = (wrow)[(kdoff) + 8];               \
    ROWFMA(v0, _wA.x, _wA.y, _wA.z);                      \
    ROWFMA(v1, _wA.w, _wB.x, _wB.y);                      \
    ROWFMA(v2, _wB.z, _wB.w, _w8);                        \
  } while (0)

#define COMPUTE_SET(ch, v0, v1, v2, v3, v4, v5, v6, v7, v8) \
  do {                                                      \
    const float* _wrow = &wl[(ch) * 48];                    \
    KD_BLOCK(_wrow, 0,  v0, v1, v2);                        \
    KD_BLOCK(_wrow, 16, v3, v4, v5);                        \
    KD_BLOCK(_wrow, 32, v6, v7, v8);                        \
  } while (0)

__global__ __launch_bounds__(256, 4)
void conv3d_chansum_reg(const float* __restrict__ x,
                        const float* __restrict__ cw,
                        const float* __restrict__ cb,
                        const float* __restrict__ pb,
                        float* __restrict__ out) {
  // weights: [32 ch][48: 3 kd-blocks of 16 (9 taps + pad)] + C at [1536]
  __shared__ float wl[1537];

  const int tid  = threadIdx.x;
  const int wid  = tid >> 6;
  const int lane = tid & 63;

  // XCD-aware bijective swizzle (1024 % 8 == 0)
  const int bid = blockIdx.x;
  const int swz = (bid & 7) * 128 + (bid >> 3);

  const int wslab = swz * 4 + wid;    // 0..4095
  const int n  = wslab >> 9;          // 0..7
  const int d  = (wslab >> 4) & 31;   // 0..31 (30,31 dead)
  const int h0 = (wslab & 15) * 4;

  const int s  = lane & 15;           // w-strip: w0 = 4s
  const int ht = lane >> 4;           // 0..3
  const bool alive = d < DOUT;        // wave-uniform

  // ---- prologue: Wsum via float4 (864 = 216*4), C via wave-0 reduce ----
  if (tid < 216) {
    const float4* cw4 = (const float4*)(cw + 4 * tid);
    float4 sum = {0.f, 0.f, 0.f, 0.f};
#pragma unroll 16
    for (int o = 0; o < 64; ++o) {
      float4 v = cw4[o * 216];   // cw + o*864 + 4*tid
      sum.x += v.x; sum.y += v.y; sum.z += v.z; sum.w += v.w;
    }
    float vs[4] = {sum.x, sum.y, sum.z, sum.w};
#pragma unroll
    for (int q = 0; q < 4; ++q) {
      int e  = 4 * tid + q;      // e = i*27 + kd*9 + t
      int i  = e / 27;
      int r  = e - i * 27;
      int kd = r / 9;
      int t  = r - kd * 9;
      wl[i * 48 + kd * 16 + t] = 0.5f * vs[q];
    }
  }
  if (tid < 64) {
    float v = 0.5f * cb[tid] + pb[tid];
#pragma unroll
    for (int off = 32; off > 0; off >>= 1) v += __shfl_xor(v, off, 64);
    if (tid == 0) wl[1536] = v;
  }
  __syncthreads();   // only barrier in the kernel
  if (!alive) return;

  const float* xn = x + (size_t)n * (32u * CH_STRIDE);

  // 9 channel-invariant strip offsets, named (no arrays anywhere).
  // h clamped: clamped rows only feed epilogue-masked outputs (h>=62).
#define OFFS(kd, kh) \
  ((d + (kd)) * (XH * XW) + min(h0 + ht + (kh), XH - 1) * XW + 4 * s)
  const int o0 = OFFS(0, 0), o1 = OFFS(0, 1), o2 = OFFS(0, 2);
  const int o3 = OFFS(1, 0), o4 = OFFS(1, 1), o5 = OFFS(1, 2);
  const int o6 = OFFS(2, 0), o7 = OFFS(2, 1), o8 = OFFS(2, 2);
#undef OFFS

  float acc0 = 0.f, acc1 = 0.f, acc2 = 0.f, acc3 = 0.f;

  float4 a0, a1, a2, a3, a4, a5, a6, a7, a8;
  float4 b0, b1, b2, b3, b4, b5, b6, b7, b8;

  // prime: A <- ch 0
  LOAD_SET(xn, a0, a1, a2, a3, a4, a5, a6, a7, a8);

#pragma unroll 1
  for (int ch = 0; ch < 32; ch += 2) {
    // issue ch+1 loads BEFORE computing ch; first a-use waits vmcnt(9)
    const float* x1 = xn + (size_t)(ch + 1) * CH_STRIDE;
    LOAD_SET(x1, b0, b1, b2, b3, b4, b5, b6, b7, b8);
    __builtin_amdgcn_sched_barrier(0);
    COMPUTE_SET(ch, a0, a1, a2, a3, a4, a5, a6, a7, a8);

    // issue ch+2 loads (dummy re-load of 31 on last pair) before compute ch+1
    const float* x2 = xn + (size_t)min(ch + 2, 31) * CH_STRIDE;
    LOAD_SET(x2, a0, a1, a2, a3, a4, a5, a6, a7, a8);
    __builtin_amdgcn_sched_barrier(0);
    COMPUTE_SET(ch + 1, b0, b1, b2, b3, b4, b5, b6, b7, b8);
  }

  // epilogue: out[n][d][h0+ht][4s..4s+3]; s=15 writes only w=60,61
  const float Cc = wl[1536];
  const int h = h0 + ht;
  if (h < HOUT) {
    float* op = out + (((size_t)n * DOUT + d) * HOUT + h) * WOUT + 4 * s;
    const int nw = min(4, WOUT - 4 * s);
    float2 v0 = {acc0 + Cc, acc1 + Cc};
    *(float2*)op = v0;                       // 8B-aligned
    if (nw == 4) {
      float2 v1 = {acc2 + Cc, acc3 + Cc};
      *(float2*)(op + 2) = v1;
    }
  }
}

extern "C" void kernel_launch(void* const* d_in, const int* in_sizes, int n_in,
                              void* d_out, int out_size, void* d_ws, size_t ws_size,
                              hipStream_t stream) {
  const float* x  = (const float*)d_in[0];  // (8,32,32,64,64)
  const float* cw = (const float*)d_in[1];  // (64,32,3,3,3)
  const float* cb = (const float*)d_in[2];  // (64,)
  const float* pb = (const float*)d_in[3];  // (64,1,1,1)
  float* out = (float*)d_out;               // (8,30,62,62)

  conv3d_chansum_reg<<<dim3(1024), 256, 0, stream>>>(x, cw, cb, pb, out);
}